// Round 1
// baseline (568.416 us; speedup 1.0000x reference)
//
#include <hip/hip_runtime.h>

#define TBLSZ (1u << 19)
#define TMASK (TBLSZ - 1u)

static __device__ __forceinline__ float sigmoidf_(float x) {
    return 1.0f / (1.0f + __expf(-x));
}

__global__ __launch_bounds__(256) void ngp_fused_kernel(
    const float* __restrict__ pos,
    const float* __restrict__ dirs,
    const float* __restrict__ table,
    const float* __restrict__ W1, const float* __restrict__ b1,
    const float* __restrict__ W2, const float* __restrict__ b2,
    const float* __restrict__ Wc1, const float* __restrict__ bc1,
    const float* __restrict__ Wc2, const float* __restrict__ bc2,
    const float* __restrict__ Wc3, const float* __restrict__ bc3,
    float* __restrict__ out, int B)
{
    const int tid = blockIdx.x * 256 + threadIdx.x;
    if (tid >= B) return;

    const float px = pos[tid*3+0];
    const float py = pos[tid*3+1];
    const float pz = pos[tid*3+2];

    // floor(16 * b^l), b = exp(ln(128)/15), replicated in float64 offline
    constexpr float RES[16] = {16.f,22.f,30.f,42.f,58.f,80.f,111.f,153.f,
                               212.f,294.f,406.f,561.f,776.f,1072.f,1482.f,2048.f};

    float enc[32];
    const float2* __restrict__ tb2 = (const float2*)table;
#pragma unroll
    for (int l = 0; l < 16; ++l) {
        const float r = RES[l];
        const float sx = px*r, sy = py*r, sz = pz*r;
        const float flx = floorf(sx), fly = floorf(sy), flz = floorf(sz);
        const float tx = sx-flx, ty = sy-fly, tz = sz-flz;
        const unsigned ix = (unsigned)(int)flx;
        const unsigned iy = (unsigned)(int)fly;
        const unsigned iz = (unsigned)(int)flz;
        const unsigned x0 = ix,               x1 = ix + 1u;
        const unsigned y0 = iy * 2654435761u, y1 = (iy+1u) * 2654435761u;
        const unsigned z0 = iz * 805459861u,  z1 = (iz+1u) * 805459861u;
        const float2* lt = tb2 + (size_t)l * TBLSZ;
        const float2 f000 = lt[(x0^y0^z0)&TMASK];
        const float2 f001 = lt[(x0^y0^z1)&TMASK];
        const float2 f010 = lt[(x0^y1^z0)&TMASK];
        const float2 f011 = lt[(x0^y1^z1)&TMASK];
        const float2 f100 = lt[(x1^y0^z0)&TMASK];
        const float2 f101 = lt[(x1^y0^z1)&TMASK];
        const float2 f110 = lt[(x1^y1^z0)&TMASK];
        const float2 f111 = lt[(x1^y1^z1)&TMASK];
        const float ux = 1.f-tx, uy = 1.f-ty, uz = 1.f-tz;
        const float w000 = ux*uy*uz, w001 = ux*uy*tz, w010 = ux*ty*uz, w011 = ux*ty*tz;
        const float w100 = tx*uy*uz, w101 = tx*uy*tz, w110 = tx*ty*uz, w111 = tx*ty*tz;
        enc[2*l+0] = w000*f000.x + w001*f001.x + w010*f010.x + w011*f011.x
                   + w100*f100.x + w101*f101.x + w110*f110.x + w111*f111.x;
        enc[2*l+1] = w000*f000.y + w001*f001.y + w010*f010.y + w011*f011.y
                   + w100*f100.y + w101*f101.y + w110*f110.y + w111*f111.y;
    }

    // density MLP: feat = relu(enc@W1+b1) @ W2 + b2   (h computed in 32-wide halves)
    float feat[16];
#pragma unroll
    for (int k = 0; k < 16; ++k) feat[k] = b2[k];
#pragma unroll
    for (int half = 0; half < 2; ++half) {
        float hacc[32];
#pragma unroll
        for (int j = 0; j < 32; ++j) hacc[j] = b1[half*32+j];
#pragma unroll
        for (int i = 0; i < 32; ++i) {
            const float e = enc[i];
#pragma unroll
            for (int j = 0; j < 32; ++j)
                hacc[j] = fmaf(e, W1[i*64 + half*32 + j], hacc[j]);
        }
#pragma unroll
        for (int j = 0; j < 32; ++j) {
            const float hj = fmaxf(hacc[j], 0.f);
#pragma unroll
            for (int k = 0; k < 16; ++k)
                feat[k] = fmaf(hj, W2[(half*32+j)*16 + k], feat[k]);
        }
    }
    const float density = __expf(feat[0]);

    // SH basis of direction
    const float dx = dirs[tid*3+0];
    const float dy = dirs[tid*3+1];
    const float dz = dirs[tid*3+2];
    const float xx = dx*dx, yy = dy*dy, zz = dz*dz;
    float cin[32];
#pragma unroll
    for (int k = 0; k < 16; ++k) cin[k] = feat[k];
    cin[16] = 0.28209479177387814f;
    cin[17] = 0.4886025119029199f*dy;
    cin[18] = 0.4886025119029199f*dz;
    cin[19] = 0.4886025119029199f*dx;
    cin[20] = 1.0925484305920792f*dx*dy;
    cin[21] = 1.0925484305920792f*dy*dz;
    cin[22] = 0.9461746957575601f*zz - 0.31539156525252f;
    cin[23] = 1.0925484305920792f*dx*dz;
    cin[24] = 0.5462742152960396f*(xx-yy);
    cin[25] = 0.5900435899266435f*dy*(3.f*xx-yy);
    cin[26] = 2.890611442640554f*dx*dy*dz;
    cin[27] = 0.4570457994644658f*dy*(5.f*zz-1.f);
    cin[28] = 0.3731763325901154f*dz*(5.f*zz-3.f);
    cin[29] = 0.4570457994644658f*dx*(5.f*zz-1.f);
    cin[30] = 1.445305721320277f*dz*(xx-yy);
    cin[31] = 0.5900435899266435f*dx*(xx-3.f*yy);

    // color layer 1: c1 = relu(cin @ Wc1 + bc1)
    float c1v[64];
#pragma unroll
    for (int j = 0; j < 64; ++j) c1v[j] = bc1[j];
#pragma unroll
    for (int i = 0; i < 32; ++i) {
        const float e = cin[i];
#pragma unroll
        for (int j = 0; j < 64; ++j)
            c1v[j] = fmaf(e, Wc1[i*64+j], c1v[j]);
    }
#pragma unroll
    for (int j = 0; j < 64; ++j) c1v[j] = fmaxf(c1v[j], 0.f);

    // color layer 2 (+output layer fused, 32-wide halves to cap live VGPRs)
    float r0 = bc3[0], r1 = bc3[1], r2 = bc3[2];
#pragma unroll
    for (int half = 0; half < 2; ++half) {
        float acc[32];
#pragma unroll
        for (int j = 0; j < 32; ++j) acc[j] = bc2[half*32+j];
#pragma unroll
        for (int i = 0; i < 64; ++i) {
            const float e = c1v[i];
#pragma unroll
            for (int j = 0; j < 32; ++j)
                acc[j] = fmaf(e, Wc2[i*64 + half*32 + j], acc[j]);
        }
#pragma unroll
        for (int j = 0; j < 32; ++j) {
            const float cj = fmaxf(acc[j], 0.f);
            const int jj = half*32 + j;
            r0 = fmaf(cj, Wc3[jj*3+0], r0);
            r1 = fmaf(cj, Wc3[jj*3+1], r1);
            r2 = fmaf(cj, Wc3[jj*3+2], r2);
        }
    }

    out[tid*3+0] = sigmoidf_(r0);
    out[tid*3+1] = sigmoidf_(r1);
    out[tid*3+2] = sigmoidf_(r2);
    out[(size_t)B*3 + tid] = density;
}

extern "C" void kernel_launch(void* const* d_in, const int* in_sizes, int n_in,
                              void* d_out, int out_size, void* d_ws, size_t ws_size,
                              hipStream_t stream)
{
    const float* pos   = (const float*)d_in[0];
    const float* dirs  = (const float*)d_in[1];
    const float* table = (const float*)d_in[2];
    const float* W1    = (const float*)d_in[3];
    const float* b1    = (const float*)d_in[4];
    const float* W2    = (const float*)d_in[5];
    const float* b2    = (const float*)d_in[6];
    const float* Wc1   = (const float*)d_in[7];
    const float* bc1   = (const float*)d_in[8];
    const float* Wc2   = (const float*)d_in[9];
    const float* bc2   = (const float*)d_in[10];
    const float* Wc3   = (const float*)d_in[11];
    const float* bc3   = (const float*)d_in[12];
    const int B = in_sizes[0] / 3;

    dim3 grid((B + 255) / 256), block(256);
    hipLaunchKernelGGL(ngp_fused_kernel, grid, block, 0, stream,
                       pos, dirs, table, W1, b1, W2, b2,
                       Wc1, bc1, Wc2, bc2, Wc3, bc3,
                       (float*)d_out, B);
}

// Round 2
// 484.868 us; speedup vs baseline: 1.1723x; 1.1723x over previous
//
#include <hip/hip_runtime.h>
#include <stdint.h>

#define TBLSZ (1u << 19)
#define TMASK (TBLSZ - 1u)

static __device__ __forceinline__ float sigmoidf_(float x) {
    return 1.0f / (1.0f + __expf(-x));
}

// floor(16 * b^l), b = exp(ln(128)/15), replicated in float64 offline
#define RES_LIST {16.f,22.f,30.f,42.f,58.f,80.f,111.f,153.f, \
                  212.f,294.f,406.f,561.f,776.f,1072.f,1482.f,2048.f}

static __device__ __forceinline__ void level_idx(
    float px, float py, float pz, float r,
    unsigned idx[8], float fr[3])
{
    const float sx = px*r, sy = py*r, sz = pz*r;
    const float flx = floorf(sx), fly = floorf(sy), flz = floorf(sz);
    fr[0] = sx-flx; fr[1] = sy-fly; fr[2] = sz-flz;
    const unsigned ix = (unsigned)(int)flx;
    const unsigned iy = (unsigned)(int)fly;
    const unsigned iz = (unsigned)(int)flz;
    const unsigned x0 = ix,               x1 = ix + 1u;
    const unsigned y0 = iy * 2654435761u, y1 = (iy+1u) * 2654435761u;
    const unsigned z0 = iz * 805459861u,  z1 = (iz+1u) * 805459861u;
    idx[0] = (x0^y0^z0)&TMASK; idx[1] = (x0^y0^z1)&TMASK;
    idx[2] = (x0^y1^z0)&TMASK; idx[3] = (x0^y1^z1)&TMASK;
    idx[4] = (x1^y0^z0)&TMASK; idx[5] = (x1^y0^z1)&TMASK;
    idx[6] = (x1^y1^z0)&TMASK; idx[7] = (x1^y1^z1)&TMASK;
}

// -------- table repack: fp32 float2 -> packed 2xbf16 (RNE) --------
__global__ __launch_bounds__(256) void cvt_table_kernel(
    const float2* __restrict__ in, uint32_t* __restrict__ outp, int n)
{
    const int i = blockIdx.x * 256 + threadIdx.x;
    if (i >= n) return;
    const float2 v = in[i];
    uint32_t bx = __float_as_uint(v.x);
    bx = (bx + 0x7fffu + ((bx >> 16) & 1u)) >> 16;
    uint32_t by = __float_as_uint(v.y);
    by = (by + 0x7fffu + ((by >> 16) & 1u)) >> 16;
    outp[i] = bx | (by << 16);
}

// -------- shared MLP tail (identical math to round-1, verified) --------
static __device__ __forceinline__ void mlp_tail(
    int tid, const float enc[32],
    const float* __restrict__ dirs,
    const float* __restrict__ W1, const float* __restrict__ b1,
    const float* __restrict__ W2, const float* __restrict__ b2,
    const float* __restrict__ Wc1, const float* __restrict__ bc1,
    const float* __restrict__ Wc2, const float* __restrict__ bc2,
    const float* __restrict__ Wc3, const float* __restrict__ bc3,
    float* __restrict__ out, int B)
{
    float feat[16];
#pragma unroll
    for (int k = 0; k < 16; ++k) feat[k] = b2[k];
#pragma unroll
    for (int half = 0; half < 2; ++half) {
        float hacc[32];
#pragma unroll
        for (int j = 0; j < 32; ++j) hacc[j] = b1[half*32+j];
#pragma unroll
        for (int i = 0; i < 32; ++i) {
            const float e = enc[i];
#pragma unroll
            for (int j = 0; j < 32; ++j)
                hacc[j] = fmaf(e, W1[i*64 + half*32 + j], hacc[j]);
        }
#pragma unroll
        for (int j = 0; j < 32; ++j) {
            const float hj = fmaxf(hacc[j], 0.f);
#pragma unroll
            for (int k = 0; k < 16; ++k)
                feat[k] = fmaf(hj, W2[(half*32+j)*16 + k], feat[k]);
        }
    }
    const float density = __expf(feat[0]);

    const float dx = dirs[tid*3+0];
    const float dy = dirs[tid*3+1];
    const float dz = dirs[tid*3+2];
    const float xx = dx*dx, yy = dy*dy, zz = dz*dz;
    float cin[32];
#pragma unroll
    for (int k = 0; k < 16; ++k) cin[k] = feat[k];
    cin[16] = 0.28209479177387814f;
    cin[17] = 0.4886025119029199f*dy;
    cin[18] = 0.4886025119029199f*dz;
    cin[19] = 0.4886025119029199f*dx;
    cin[20] = 1.0925484305920792f*dx*dy;
    cin[21] = 1.0925484305920792f*dy*dz;
    cin[22] = 0.9461746957575601f*zz - 0.31539156525252f;
    cin[23] = 1.0925484305920792f*dx*dz;
    cin[24] = 0.5462742152960396f*(xx-yy);
    cin[25] = 0.5900435899266435f*dy*(3.f*xx-yy);
    cin[26] = 2.890611442640554f*dx*dy*dz;
    cin[27] = 0.4570457994644658f*dy*(5.f*zz-1.f);
    cin[28] = 0.3731763325901154f*dz*(5.f*zz-3.f);
    cin[29] = 0.4570457994644658f*dx*(5.f*zz-1.f);
    cin[30] = 1.445305721320277f*dz*(xx-yy);
    cin[31] = 0.5900435899266435f*dx*(xx-3.f*yy);

    float c1v[64];
#pragma unroll
    for (int j = 0; j < 64; ++j) c1v[j] = bc1[j];
#pragma unroll
    for (int i = 0; i < 32; ++i) {
        const float e = cin[i];
#pragma unroll
        for (int j = 0; j < 64; ++j)
            c1v[j] = fmaf(e, Wc1[i*64+j], c1v[j]);
    }
#pragma unroll
    for (int j = 0; j < 64; ++j) c1v[j] = fmaxf(c1v[j], 0.f);

    float r0 = bc3[0], r1 = bc3[1], r2 = bc3[2];
#pragma unroll
    for (int half = 0; half < 2; ++half) {
        float acc[32];
#pragma unroll
        for (int j = 0; j < 32; ++j) acc[j] = bc2[half*32+j];
#pragma unroll
        for (int i = 0; i < 64; ++i) {
            const float e = c1v[i];
#pragma unroll
            for (int j = 0; j < 32; ++j)
                acc[j] = fmaf(e, Wc2[i*64 + half*32 + j], acc[j]);
        }
#pragma unroll
        for (int j = 0; j < 32; ++j) {
            const float cj = fmaxf(acc[j], 0.f);
            const int jj = half*32 + j;
            r0 = fmaf(cj, Wc3[jj*3+0], r0);
            r1 = fmaf(cj, Wc3[jj*3+1], r1);
            r2 = fmaf(cj, Wc3[jj*3+2], r2);
        }
    }

    out[tid*3+0] = sigmoidf_(r0);
    out[tid*3+1] = sigmoidf_(r1);
    out[tid*3+2] = sigmoidf_(r2);
    out[(size_t)B*3 + tid] = density;
}

// -------- main kernel: bf16-packed table + one-level gather prefetch --------
__global__ __launch_bounds__(256) void ngp_fused_bf16_kernel(
    const float* __restrict__ pos,
    const float* __restrict__ dirs,
    const uint32_t* __restrict__ tbl,
    const float* __restrict__ W1, const float* __restrict__ b1,
    const float* __restrict__ W2, const float* __restrict__ b2,
    const float* __restrict__ Wc1, const float* __restrict__ bc1,
    const float* __restrict__ Wc2, const float* __restrict__ bc2,
    const float* __restrict__ Wc3, const float* __restrict__ bc3,
    float* __restrict__ out, int B)
{
    const int tid = blockIdx.x * 256 + threadIdx.x;
    if (tid >= B) return;

    const float px = pos[tid*3+0];
    const float py = pos[tid*3+1];
    const float pz = pos[tid*3+2];

    constexpr float RES[16] = RES_LIST;

    float enc[32];

    // prologue: issue level-0 gathers
    unsigned idx[8]; float frc[3];
    level_idx(px, py, pz, RES[0], idx, frc);
    uint32_t buf[8];
#pragma unroll
    for (int c = 0; c < 8; ++c) buf[c] = tbl[idx[c]];

#pragma unroll
    for (int l = 0; l < 16; ++l) {
        uint32_t nbuf[8]; float nfr[3];
        if (l < 15) {
            unsigned nidx[8];
            level_idx(px, py, pz, RES[l+1], nidx, nfr);
            const uint32_t* nlt = tbl + (size_t)(l+1) * TBLSZ;
#pragma unroll
            for (int c = 0; c < 8; ++c) nbuf[c] = nlt[nidx[c]];
        }
        // consume current level
        const float tx = frc[0], ty = frc[1], tz = frc[2];
        const float ux = 1.f-tx, uy = 1.f-ty, uz = 1.f-tz;
        const float w[8] = { ux*uy*uz, ux*uy*tz, ux*ty*uz, ux*ty*tz,
                             tx*uy*uz, tx*uy*tz, tx*ty*uz, tx*ty*tz };
        float ex = 0.f, ey = 0.f;
#pragma unroll
        for (int c = 0; c < 8; ++c) {
            const float fx = __uint_as_float(buf[c] << 16);
            const float fy = __uint_as_float(buf[c] & 0xffff0000u);
            ex = fmaf(w[c], fx, ex);
            ey = fmaf(w[c], fy, ey);
        }
        enc[2*l+0] = ex;
        enc[2*l+1] = ey;
        if (l < 15) {
#pragma unroll
            for (int c = 0; c < 8; ++c) buf[c] = nbuf[c];
            frc[0] = nfr[0]; frc[1] = nfr[1]; frc[2] = nfr[2];
        }
    }

    mlp_tail(tid, enc, dirs, W1, b1, W2, b2, Wc1, bc1, Wc2, bc2, Wc3, bc3, out, B);
}

// -------- fallback: fp32 table (round-1 verified path), used if ws too small --------
__global__ __launch_bounds__(256) void ngp_fused_fp32_kernel(
    const float* __restrict__ pos,
    const float* __restrict__ dirs,
    const float* __restrict__ table,
    const float* __restrict__ W1, const float* __restrict__ b1,
    const float* __restrict__ W2, const float* __restrict__ b2,
    const float* __restrict__ Wc1, const float* __restrict__ bc1,
    const float* __restrict__ Wc2, const float* __restrict__ bc2,
    const float* __restrict__ Wc3, const float* __restrict__ bc3,
    float* __restrict__ out, int B)
{
    const int tid = blockIdx.x * 256 + threadIdx.x;
    if (tid >= B) return;

    const float px = pos[tid*3+0];
    const float py = pos[tid*3+1];
    const float pz = pos[tid*3+2];

    constexpr float RES[16] = RES_LIST;

    float enc[32];
    const float2* __restrict__ tb2 = (const float2*)table;
#pragma unroll
    for (int l = 0; l < 16; ++l) {
        unsigned idx[8]; float fr[3];
        level_idx(px, py, pz, RES[l], idx, fr);
        const float2* lt = tb2 + (size_t)l * TBLSZ;
        float2 f[8];
#pragma unroll
        for (int c = 0; c < 8; ++c) f[c] = lt[idx[c]];
        const float tx = fr[0], ty = fr[1], tz = fr[2];
        const float ux = 1.f-tx, uy = 1.f-ty, uz = 1.f-tz;
        const float w[8] = { ux*uy*uz, ux*uy*tz, ux*ty*uz, ux*ty*tz,
                             tx*uy*uz, tx*uy*tz, tx*ty*uz, tx*ty*tz };
        float ex = 0.f, ey = 0.f;
#pragma unroll
        for (int c = 0; c < 8; ++c) {
            ex = fmaf(w[c], f[c].x, ex);
            ey = fmaf(w[c], f[c].y, ey);
        }
        enc[2*l+0] = ex;
        enc[2*l+1] = ey;
    }

    mlp_tail(tid, enc, dirs, W1, b1, W2, b2, Wc1, bc1, Wc2, bc2, Wc3, bc3, out, B);
}

extern "C" void kernel_launch(void* const* d_in, const int* in_sizes, int n_in,
                              void* d_out, int out_size, void* d_ws, size_t ws_size,
                              hipStream_t stream)
{
    const float* pos   = (const float*)d_in[0];
    const float* dirs  = (const float*)d_in[1];
    const float* table = (const float*)d_in[2];
    const float* W1    = (const float*)d_in[3];
    const float* b1    = (const float*)d_in[4];
    const float* W2    = (const float*)d_in[5];
    const float* b2    = (const float*)d_in[6];
    const float* Wc1   = (const float*)d_in[7];
    const float* bc1   = (const float*)d_in[8];
    const float* Wc2   = (const float*)d_in[9];
    const float* bc2   = (const float*)d_in[10];
    const float* Wc3   = (const float*)d_in[11];
    const float* bc3   = (const float*)d_in[12];
    const int B = in_sizes[0] / 3;

    const int n_entries = 16 * (int)TBLSZ;               // 8388608
    const size_t need = (size_t)n_entries * sizeof(uint32_t);  // 32 MB

    dim3 block(256);
    if (ws_size >= need) {
        uint32_t* tbl_bf16 = (uint32_t*)d_ws;
        dim3 cgrid((n_entries + 255) / 256);
        hipLaunchKernelGGL(cvt_table_kernel, cgrid, block, 0, stream,
                           (const float2*)table, tbl_bf16, n_entries);
        dim3 grid((B + 255) / 256);
        hipLaunchKernelGGL(ngp_fused_bf16_kernel, grid, block, 0, stream,
                           pos, dirs, tbl_bf16, W1, b1, W2, b2,
                           Wc1, bc1, Wc2, bc2, Wc3, bc3,
                           (float*)d_out, B);
    } else {
        dim3 grid((B + 255) / 256);
        hipLaunchKernelGGL(ngp_fused_fp32_kernel, grid, block, 0, stream,
                           pos, dirs, table, W1, b1, W2, b2,
                           Wc1, bc1, Wc2, bc2, Wc3, bc3,
                           (float*)d_out, B);
    }
}